// Round 7
// baseline (182.397 us; speedup 1.0000x reference)
//
#include <hip/hip_runtime.h>
#include <hip/hip_bf16.h>
#include <stdint.h>

#define SEQ 2048
#define DIM 1024
#define HEADS 16
#define HD 64
#define NEGV (-1e9f)

typedef __attribute__((ext_vector_type(8))) short short8;
typedef __attribute__((ext_vector_type(4))) float f32x4;

__device__ __forceinline__ unsigned short f2bf(float f) {
  __hip_bfloat16 h = __float2bfloat16(f);
  union { __hip_bfloat16 h; unsigned short u; } cv;
  cv.h = h;
  return cv.u;
}

__device__ __forceinline__ void async16(const void* g, void* l) {
  __builtin_amdgcn_global_load_lds(
      (const __attribute__((address_space(1))) unsigned int*)g,
      (__attribute__((address_space(3))) unsigned int*)l, 16, 0, 0);
}

// ---------- fp32 -> bf16 cast, float4 vectorized ----------
__global__ void cast_bf16_k(const float* __restrict__ in,
                            unsigned short* __restrict__ out, int n4) {
  int stride = gridDim.x * blockDim.x;
  for (int i = blockIdx.x * blockDim.x + threadIdx.x; i < n4; i += stride) {
    float4 v = ((const float4*)in)[i];
    ushort4 o;
    o.x = f2bf(v.x); o.y = f2bf(v.y); o.z = f2bf(v.z); o.w = f2bf(v.w);
    ((ushort4*)out)[i] = o;
  }
}

// fused 4-weight cast: blockIdx.y selects the matrix
__global__ void cast_w4_k(const float* __restrict__ w0, const float* __restrict__ w1,
                          const float* __restrict__ w2, const float* __restrict__ w3,
                          unsigned short* __restrict__ o0, unsigned short* __restrict__ o1,
                          unsigned short* __restrict__ o2, unsigned short* __restrict__ o3,
                          int n4) {
  const float* in = (blockIdx.y == 0) ? w0 : (blockIdx.y == 1) ? w1
                   : (blockIdx.y == 2) ? w2 : w3;
  unsigned short* out = (blockIdx.y == 0) ? o0 : (blockIdx.y == 1) ? o1
                       : (blockIdx.y == 2) ? o2 : o3;
  int stride = gridDim.x * blockDim.x;
  for (int i = blockIdx.x * blockDim.x + threadIdx.x; i < n4; i += stride) {
    float4 v = ((const float4*)in)[i];
    ushort4 o;
    o.x = f2bf(v.x); o.y = f2bf(v.y); o.z = f2bf(v.z); o.w = f2bf(v.w);
    ((ushort4*)out)[i] = o;
  }
}

// ---------- shared GEMM core: C[128x128] tile, A[M,K] bf16, B[N,K] bf16 (B^T input) ----------
__device__ __forceinline__ void gemm_core(const unsigned short* __restrict__ A,
                                          const unsigned short* __restrict__ B,
                                          int K, int bm0, int bn0,
                                          unsigned short* As, unsigned short* Bs,
                                          f32x4 acc[4][4]) {
  const int tid  = threadIdx.x;
  const int lane = tid & 63;
  const int w    = tid >> 6;
  const int wr   = w >> 1, wc = w & 1;
  const int lrow = lane & 15, lkg = lane >> 4;

  for (int k0 = 0; k0 < K; k0 += 32) {
#pragma unroll
    for (int i = 0; i < 2; ++i) {
      int e   = (i * 256 + tid) * 8;
      int row = e >> 5;
      int kk  = e & 31;
      async16(A + (size_t)(bm0 + row) * K + (size_t)(k0 + kk), As + e);
      async16(B + (size_t)(bn0 + row) * K + (size_t)(k0 + kk), Bs + e);
    }
    __syncthreads();

    short8 af[4], bf[4];
#pragma unroll
    for (int i = 0; i < 4; ++i) {
      af[i] = *(const short8*)(As + (wr * 64 + i * 16 + lrow) * 32 + lkg * 8);
      bf[i] = *(const short8*)(Bs + (wc * 64 + i * 16 + lrow) * 32 + lkg * 8);
    }
#pragma unroll
    for (int i = 0; i < 4; ++i)
#pragma unroll
      for (int j = 0; j < 4; ++j)
        acc[i][j] = __builtin_amdgcn_mfma_f32_16x16x32_bf16(af[i], bf[j], acc[i][j], 0, 0, 0);
    __syncthreads();
  }
}

// ---------- fused QKV projection ----------
__global__ __launch_bounds__(256)
void qkv_gemm_k(const unsigned short* __restrict__ xb,
                const unsigned short* __restrict__ wqb,
                const unsigned short* __restrict__ wkb,
                const unsigned short* __restrict__ wvb,
                const float* __restrict__ bq, const float* __restrict__ bk,
                const float* __restrict__ bv,
                unsigned short* __restrict__ Qb, unsigned short* __restrict__ Kb,
                unsigned short* __restrict__ Vtb) {
  __shared__ __align__(16) unsigned short As[128 * 32];
  __shared__ __align__(16) unsigned short Bs[128 * 32];
  const int z = blockIdx.z;
  const unsigned short* B = (z == 0) ? wqb : (z == 1) ? wkb : wvb;
  const float* bias       = (z == 0) ? bq  : (z == 1) ? bk  : bv;
  const int bm0 = blockIdx.y * 128, bn0 = blockIdx.x * 128;

  f32x4 acc[4][4] = {};
  gemm_core(xb, B, DIM, bm0, bn0, As, Bs, acc);

  const int lane = threadIdx.x & 63;
  const int w = threadIdx.x >> 6, wr = w >> 1, wc = w & 1;
  unsigned short* out01 = (z == 0) ? Qb : Kb;
#pragma unroll
  for (int i = 0; i < 4; ++i)
#pragma unroll
    for (int j = 0; j < 4; ++j)
#pragma unroll
      for (int r = 0; r < 4; ++r) {
        int mg = bm0 + wr * 64 + i * 16 + (lane >> 4) * 4 + r;
        int ng = bn0 + wc * 64 + j * 16 + (lane & 15);
        float v = acc[i][j][r] + bias[ng];
        int bb = mg >> 11, s = mg & 2047, h = ng >> 6, d = ng & 63;
        int bh = bb * HEADS + h;
        if (z < 2)
          out01[((size_t)bh * SEQ + s) * HD + d] = f2bf(v);   // [b,h,s,d]
        else
          Vtb[((size_t)bh * HD + d) * SEQ + s] = f2bf(v);     // [b,h,d,s]
      }
}

// ---------- output projection (fp32 out + bias) ----------
__global__ __launch_bounds__(256)
void out_gemm_k(const unsigned short* __restrict__ Ob,
                const unsigned short* __restrict__ wob,
                const float* __restrict__ bo, float* __restrict__ out) {
  __shared__ __align__(16) unsigned short As[128 * 32];
  __shared__ __align__(16) unsigned short Bs[128 * 32];
  const int bm0 = blockIdx.y * 128, bn0 = blockIdx.x * 128;

  f32x4 acc[4][4] = {};
  gemm_core(Ob, wob, DIM, bm0, bn0, As, Bs, acc);

  const int lane = threadIdx.x & 63;
  const int w = threadIdx.x >> 6, wr = w >> 1, wc = w & 1;
#pragma unroll
  for (int i = 0; i < 4; ++i)
#pragma unroll
    for (int j = 0; j < 4; ++j)
#pragma unroll
      for (int r = 0; r < 4; ++r) {
        int mg = bm0 + wr * 64 + i * 16 + (lane >> 4) * 4 + r;
        int ng = bn0 + wc * 64 + j * 16 + (lane & 15);
        out[(size_t)mg * DIM + ng] = acc[i][j][r] + bo[ng];
      }
}

// ---------- flash attention: in-block k-split, 8 waves, KVBLK=32 ----------
// grid (32, 32) x 512 threads. Block = q-tile qb (64 rows), bh.
// Waves 0-3: rows (w&3)*16, k-tiles [0, NH). Waves 4-7: same rows, [NH, 2NH).
// nk32 = 2(qb+1) is always even -> halves exactly equal, NH = qb+1 lockstep
// iterations. Double-buffered staging (pre-swizzled source, linear dest).
// Halves merged at the end via an in-LDS (m,l,O) combine.
// LDS: K 2x2x4KB + V 2x2x4KB + P 8x1KB = 40960 B.
__global__ __launch_bounds__(512, 4)
void attn_k(const unsigned short* __restrict__ Q,
            const unsigned short* __restrict__ Kp,
            const unsigned short* __restrict__ Vt,
            const int* __restrict__ pm,
            unsigned short* __restrict__ O) {
  __shared__ __align__(16) unsigned short smem[20480];   // 40 KB

  const int tid  = threadIdx.x;
  const int lane = tid & 63;
  const int w    = tid >> 6;          // 0..7
  const int half = w >> 2, wq = w & 3;
  const int lc = lane & 15, lg = lane >> 4;
  const int bx = blockIdx.x, bh = blockIdx.y;
  const int b = bh >> 4, h = bh & 15;
  const int qb = (bx & 1) ? (31 - (bx >> 1)) : (bx >> 1);  // pairing balance
  const int NH = qb + 1;              // iterations = tiles per half (KVBLK=32)

  const size_t base = (size_t)bh * SEQ * HD;
  const unsigned short* kbase = Kp + base;
  const unsigned short* vbase = Vt + (size_t)bh * HD * SEQ;
  const int* pmb = pm + b * SEQ;

  unsigned short* Ksm = smem;          // [half*2+buf][2048]  (K: [32 k][64 d])
  unsigned short* Vsm = smem + 8192;   // [half*2+buf][2048]  (V: [64 d][32 k])
  char* pb = (char*)(smem + 16384 + w * 512);   // per-wave P [16 q][32 k]
  const int swp = (lc & 3) << 4;

  const int qrow0 = qb * 64 + wq * 16;
  const int qrow  = qrow0 + lc;

  short8 qa[2];
  {
    const unsigned short* qp = Q + base + (size_t)qrow * HD + lg * 8;
    qa[0] = *(const short8*)(qp);
    qa[1] = *(const short8*)(qp + 32);
  }

  f32x4 oacc[4] = {};
  float mrow = -1e30f, lsum = 0.f;

  // staging: thread handles one K chunk + one V chunk of half hs = tid>>8
  const int hs = tid >> 8;
  const int c  = tid & 255;
  const int krow = c >> 3, kslot = c & 7;              // K: 32 rows x 8 slots
  const int vd   = c >> 2, vslot = c & 3;              // V: 64 rows x 4 slots
  const unsigned short* ksrc0 = kbase + (size_t)krow * HD + (kslot ^ (krow & 7)) * 8;
  const unsigned short* vsrc0 = vbase + (size_t)vd * SEQ + (vslot ^ (vd & 3)) * 8;

#define STAGE_PAIR(it, buf)                                                  \
  {                                                                          \
    const int tg = hs ? (NH + (it)) : (it);                                  \
    async16(ksrc0 + (size_t)(tg * 32) * HD,                                  \
            Ksm + (hs * 2 + (buf)) * 2048 + c * 8);                          \
    async16(vsrc0 + tg * 32, Vsm + (hs * 2 + (buf)) * 2048 + c * 8);         \
  }

  STAGE_PAIR(0, 0);
  __syncthreads();   // DMA(0) drained

  for (int i = 0; i < NH; ++i) {
    const int cur = i & 1;
    if (i + 1 < NH) STAGE_PAIR(i + 1, cur ^ 1);

    const int tb = half * NH + i;       // this wave's global k-tile
    const int k0 = tb * 32;
    const bool causal = (tb >= 2 * qb); // only the two diagonal tiles

    // ---- QK^T swapped: mfma(K, Q) -> lane holds S[q=lc][k-slice] ----
    const char* kbuf = (const char*)(Ksm + (half * 2 + cur) * 2048);
    f32x4 s[2];
#pragma unroll
    for (int t = 0; t < 2; ++t) {
      const int row = t * 16 + lc;
      const int swk = (row & 7) << 4;
      const char* kr = kbuf + row * 128;
      short8 kb0 = *(const short8*)(kr + ((lg * 16) ^ swk));
      short8 kb1 = *(const short8*)(kr + ((64 + lg * 16) ^ swk));
      f32x4 z = {};
      z = __builtin_amdgcn_mfma_f32_16x16x32_bf16(kb0, qa[0], z, 0, 0, 0);
      z = __builtin_amdgcn_mfma_f32_16x16x32_bf16(kb1, qa[1], z, 0, 0, 0);
      const int kr0 = k0 + t * 16;
      int4 pmv = *(const int4*)(pmb + kr0 + lg * 4);
#pragma unroll
      for (int r = 0; r < 4; ++r) {
        const int kidx = kr0 + lg * 4 + r;
        float sv = z[r] * 0.125f;                       // 1/sqrt(64)
        if ((causal && kidx > qrow) || (&pmv.x)[r] == 0) sv = NEGV;
        s[t][r] = sv;
      }
    }

    // ---- online softmax over 8 values + 2 shuffles, defer-max rescale ----
    float mx = fmaxf(fmaxf(fmaxf(s[0][0], s[0][1]), fmaxf(s[0][2], s[0][3])),
                     fmaxf(fmaxf(s[1][0], s[1][1]), fmaxf(s[1][2], s[1][3])));
    mx = fmaxf(mx, __shfl_xor(mx, 16, 64));
    mx = fmaxf(mx, __shfl_xor(mx, 32, 64));
    if (!__all(mx <= mrow + 8.f)) {
      const float mnew = fmaxf(mrow, mx);
      const float sc = __expf(mrow - mnew);
      lsum *= sc;
      mrow = mnew;
      const float s0 = __shfl(sc, lg * 4 + 0, 64);
      const float s1 = __shfl(sc, lg * 4 + 1, 64);
      const float s2 = __shfl(sc, lg * 4 + 2, 64);
      const float s3 = __shfl(sc, lg * 4 + 3, 64);
#pragma unroll
      for (int t = 0; t < 4; ++t) {
        oacc[t][0] *= s0; oacc[t][1] *= s1; oacc[t][2] *= s2; oacc[t][3] *= s3;
      }
    }
    float sum = 0.f;
#pragma unroll
    for (int t = 0; t < 2; ++t)
#pragma unroll
      for (int r = 0; r < 4; ++r) {
        const float p = __expf(s[t][r] - mrow);
        s[t][r] = p;
        sum += p;
      }
    sum += __shfl_xor(sum, 16, 64);
    sum += __shfl_xor(sum, 32, 64);
    lsum += sum;

    // ---- P -> per-wave LDS (bf16, swizzled 64B rows), wave-synchronous ----
#pragma unroll
    for (int t = 0; t < 2; ++t) {
      short4 pk;
      pk.x = (short)f2bf(s[t][0]); pk.y = (short)f2bf(s[t][1]);
      pk.z = (short)f2bf(s[t][2]); pk.w = (short)f2bf(s[t][3]);
      *(short4*)(pb + lc * 64 + ((t * 32 + lg * 8) ^ swp)) = pk;
    }
    short8 pa = *(const short8*)(pb + lc * 64 + ((lg * 16) ^ swp));

    // ---- PV: O += P @ V ----
    const char* vbuf = (const char*)(Vsm + (half * 2 + cur) * 2048);
#pragma unroll
    for (int t = 0; t < 4; ++t) {
      const int d = t * 16 + lc;
      short8 vv = *(const short8*)(vbuf + d * 64 + ((lg * 16) ^ ((d & 3) << 4)));
      oacc[t] = __builtin_amdgcn_mfma_f32_16x16x32_bf16(pa, vv, oacc[t], 0, 0, 0);
    }

    __syncthreads();   // drains stage DMA; all waves done with buf[cur]
  }

  // ---- combine halves via LDS (reuses K/V space; all DMA drained) ----
  float* xch = (float*)smem;   // 4 pairs x 64 lanes x 20 f32 = 20480 B
  if (half) {
    float* dst = xch + (wq * 64 + lane) * 20;
#pragma unroll
    for (int t = 0; t < 4; ++t) *(f32x4*)(dst + t * 4) = oacc[t];
    dst[16] = mrow; dst[17] = lsum;
  }
  __syncthreads();
  if (!half) {
    const float* src = xch + (wq * 64 + lane) * 20;
    f32x4 ob[4];
#pragma unroll
    for (int t = 0; t < 4; ++t) ob[t] = *(const f32x4*)(src + t * 4);
    const float mB = src[16], lB = src[17];
    const float mN = fmaxf(mrow, mB);
    const float aA = __expf(mrow - mN);
    const float aB = __expf(mB - mN);
    const float lN = lsum * aA + lB * aB;
#pragma unroll
    for (int r = 0; r < 4; ++r) {
      const float fa = __shfl(aA, lg * 4 + r, 64);
      const float fb = __shfl(aB, lg * 4 + r, 64);
      const float il = 1.f / __shfl(lN, lg * 4 + r, 64);
      const size_t o0 =
          ((size_t)(b * SEQ + qrow0 + lg * 4 + r)) * DIM + h * HD + lc;
#pragma unroll
      for (int t = 0; t < 4; ++t)
        O[o0 + t * 16] = f2bf((oacc[t][r] * fa + ob[t][r] * fb) * il);
    }
  }
}

extern "C" void kernel_launch(void* const* d_in, const int* in_sizes, int n_in,
                              void* d_out, int out_size, void* d_ws, size_t ws_size,
                              hipStream_t stream) {
  const float* x  = (const float*)d_in[0];
  const int*   pm = (const int*)d_in[1];
  const float* Wq = (const float*)d_in[3];
  const float* bq = (const float*)d_in[4];
  const float* Wk = (const float*)d_in[5];
  const float* bk = (const float*)d_in[6];
  const float* Wv = (const float*)d_in[7];
  const float* bv = (const float*)d_in[8];
  const float* Wo = (const float*)d_in[9];
  const float* bo = (const float*)d_in[10];

  const size_t NX = (size_t)4096 * 1024;
  const size_t NW = (size_t)1024 * 1024;

  unsigned short* ws  = (unsigned short*)d_ws;
  unsigned short* xb  = ws;
  unsigned short* wqb = xb + NX;
  unsigned short* wkb = wqb + NW;
  unsigned short* wvb = wkb + NW;
  unsigned short* wob = wvb + NW;
  unsigned short* Qb  = wob + NW;
  unsigned short* Kb  = Qb + NX;
  unsigned short* Vtb = Kb + NX;
  unsigned short* Ob  = xb;   // alias: x no longer needed after QKV GEMM

  cast_bf16_k<<<dim3(2048), dim3(256), 0, stream>>>(x, xb, (int)(NX / 4));
  cast_w4_k<<<dim3(512, 4), dim3(256), 0, stream>>>(Wq, Wk, Wv, Wo,
                                                    wqb, wkb, wvb, wob,
                                                    (int)(NW / 4));

  qkv_gemm_k<<<dim3(8, 32, 3), dim3(256), 0, stream>>>(xb, wqb, wkb, wvb,
                                                       bq, bk, bv, Qb, Kb, Vtb);

  attn_k<<<dim3(32, 32), dim3(512), 0, stream>>>(Qb, Kb, Vtb, pm, Ob);

  out_gemm_k<<<dim3(8, 32), dim3(256), 0, stream>>>(Ob, wob, bo, (float*)d_out);
}

// Round 8
// 142.691 us; speedup vs baseline: 1.2783x; 1.2783x over previous
//
#include <hip/hip_runtime.h>
#include <hip/hip_bf16.h>
#include <stdint.h>

#define SEQ 2048
#define DIM 1024
#define HEADS 16
#define HD 64
#define NEGV (-1e9f)

typedef __attribute__((ext_vector_type(8))) short short8;
typedef __attribute__((ext_vector_type(4))) float f32x4;

__device__ __forceinline__ unsigned short f2bf(float f) {
  __hip_bfloat16 h = __float2bfloat16(f);
  union { __hip_bfloat16 h; unsigned short u; } cv;
  cv.h = h;
  return cv.u;
}

__device__ __forceinline__ void async16(const void* g, void* l) {
  __builtin_amdgcn_global_load_lds(
      (const __attribute__((address_space(1))) unsigned int*)g,
      (__attribute__((address_space(3))) unsigned int*)l, 16, 0, 0);
}

// ---------- fp32 -> bf16 cast, float4 vectorized ----------
__global__ void cast_bf16_k(const float* __restrict__ in,
                            unsigned short* __restrict__ out, int n4) {
  int stride = gridDim.x * blockDim.x;
  for (int i = blockIdx.x * blockDim.x + threadIdx.x; i < n4; i += stride) {
    float4 v = ((const float4*)in)[i];
    ushort4 o;
    o.x = f2bf(v.x); o.y = f2bf(v.y); o.z = f2bf(v.z); o.w = f2bf(v.w);
    ((ushort4*)out)[i] = o;
  }
}

// fused 4-weight cast: blockIdx.y selects the matrix
__global__ void cast_w4_k(const float* __restrict__ w0, const float* __restrict__ w1,
                          const float* __restrict__ w2, const float* __restrict__ w3,
                          unsigned short* __restrict__ o0, unsigned short* __restrict__ o1,
                          unsigned short* __restrict__ o2, unsigned short* __restrict__ o3,
                          int n4) {
  const float* in = (blockIdx.y == 0) ? w0 : (blockIdx.y == 1) ? w1
                   : (blockIdx.y == 2) ? w2 : w3;
  unsigned short* out = (blockIdx.y == 0) ? o0 : (blockIdx.y == 1) ? o1
                       : (blockIdx.y == 2) ? o2 : o3;
  int stride = gridDim.x * blockDim.x;
  for (int i = blockIdx.x * blockDim.x + threadIdx.x; i < n4; i += stride) {
    float4 v = ((const float4*)in)[i];
    ushort4 o;
    o.x = f2bf(v.x); o.y = f2bf(v.y); o.z = f2bf(v.z); o.w = f2bf(v.w);
    ((ushort4*)out)[i] = o;
  }
}

// ---------- shared GEMM core: C[128x128] tile, A[M,K] bf16, B[N,K] bf16 (B^T input) ----------
__device__ __forceinline__ void gemm_core(const unsigned short* __restrict__ A,
                                          const unsigned short* __restrict__ B,
                                          int K, int bm0, int bn0,
                                          unsigned short* As, unsigned short* Bs,
                                          f32x4 acc[4][4]) {
  const int tid  = threadIdx.x;
  const int lane = tid & 63;
  const int w    = tid >> 6;
  const int wr   = w >> 1, wc = w & 1;
  const int lrow = lane & 15, lkg = lane >> 4;

  for (int k0 = 0; k0 < K; k0 += 32) {
#pragma unroll
    for (int i = 0; i < 2; ++i) {
      int e   = (i * 256 + tid) * 8;
      int row = e >> 5;
      int kk  = e & 31;
      async16(A + (size_t)(bm0 + row) * K + (size_t)(k0 + kk), As + e);
      async16(B + (size_t)(bn0 + row) * K + (size_t)(k0 + kk), Bs + e);
    }
    __syncthreads();

    short8 af[4], bf[4];
#pragma unroll
    for (int i = 0; i < 4; ++i) {
      af[i] = *(const short8*)(As + (wr * 64 + i * 16 + lrow) * 32 + lkg * 8);
      bf[i] = *(const short8*)(Bs + (wc * 64 + i * 16 + lrow) * 32 + lkg * 8);
    }
#pragma unroll
    for (int i = 0; i < 4; ++i)
#pragma unroll
      for (int j = 0; j < 4; ++j)
        acc[i][j] = __builtin_amdgcn_mfma_f32_16x16x32_bf16(af[i], bf[j], acc[i][j], 0, 0, 0);
    __syncthreads();
  }
}

// ---------- fused QKV projection ----------
__global__ __launch_bounds__(256)
void qkv_gemm_k(const unsigned short* __restrict__ xb,
                const unsigned short* __restrict__ wqb,
                const unsigned short* __restrict__ wkb,
                const unsigned short* __restrict__ wvb,
                const float* __restrict__ bq, const float* __restrict__ bk,
                const float* __restrict__ bv,
                unsigned short* __restrict__ Qb, unsigned short* __restrict__ Kb,
                unsigned short* __restrict__ Vtb) {
  __shared__ __align__(16) unsigned short As[128 * 32];
  __shared__ __align__(16) unsigned short Bs[128 * 32];
  const int z = blockIdx.z;
  const unsigned short* B = (z == 0) ? wqb : (z == 1) ? wkb : wvb;
  const float* bias       = (z == 0) ? bq  : (z == 1) ? bk  : bv;
  const int bm0 = blockIdx.y * 128, bn0 = blockIdx.x * 128;

  f32x4 acc[4][4] = {};
  gemm_core(xb, B, DIM, bm0, bn0, As, Bs, acc);

  const int lane = threadIdx.x & 63;
  const int w = threadIdx.x >> 6, wr = w >> 1, wc = w & 1;
  unsigned short* out01 = (z == 0) ? Qb : Kb;
#pragma unroll
  for (int i = 0; i < 4; ++i)
#pragma unroll
    for (int j = 0; j < 4; ++j)
#pragma unroll
      for (int r = 0; r < 4; ++r) {
        int mg = bm0 + wr * 64 + i * 16 + (lane >> 4) * 4 + r;
        int ng = bn0 + wc * 64 + j * 16 + (lane & 15);
        float v = acc[i][j][r] + bias[ng];
        int bb = mg >> 11, s = mg & 2047, h = ng >> 6, d = ng & 63;
        int bh = bb * HEADS + h;
        if (z < 2)
          out01[((size_t)bh * SEQ + s) * HD + d] = f2bf(v);   // [b,h,s,d]
        else
          Vtb[((size_t)bh * HD + d) * SEQ + s] = f2bf(v);     // [b,h,d,s]
      }
}

// ---------- output projection (fp32 out + bias) ----------
__global__ __launch_bounds__(256)
void out_gemm_k(const unsigned short* __restrict__ Ob,
                const unsigned short* __restrict__ wob,
                const float* __restrict__ bo, float* __restrict__ out) {
  __shared__ __align__(16) unsigned short As[128 * 32];
  __shared__ __align__(16) unsigned short Bs[128 * 32];
  const int bm0 = blockIdx.y * 128, bn0 = blockIdx.x * 128;

  f32x4 acc[4][4] = {};
  gemm_core(Ob, wob, DIM, bm0, bn0, As, Bs, acc);

  const int lane = threadIdx.x & 63;
  const int w = threadIdx.x >> 6, wr = w >> 1, wc = w & 1;
#pragma unroll
  for (int i = 0; i < 4; ++i)
#pragma unroll
    for (int j = 0; j < 4; ++j)
#pragma unroll
      for (int r = 0; r < 4; ++r) {
        int mg = bm0 + wr * 64 + i * 16 + (lane >> 4) * 4 + r;
        int ng = bn0 + wc * 64 + j * 16 + (lane & 15);
        out[(size_t)mg * DIM + ng] = acc[i][j][r] + bo[ng];
      }
}

// ---------- attention: KVBLK=64 staging, swizzled source ----------
__device__ __forceinline__ void stage_kv64(const unsigned short* __restrict__ kbase,
                                           const unsigned short* __restrict__ vbase,
                                           int k0, unsigned short* KsB,
                                           unsigned short* VsB, int tid) {
#pragma unroll
  for (int j = 0; j < 2; ++j) {
    const int c    = j * 256 + tid;   // 512 chunks of 16B: K[64][64]
    const int row  = c >> 3;
    const int colb = (c & 7) << 4;
    const int srcb = colb ^ ((row & 7) << 4);
    async16(kbase + (size_t)(k0 + row) * HD + (srcb >> 1), KsB + c * 8);
  }
#pragma unroll
  for (int j = 0; j < 2; ++j) {
    const int c    = j * 256 + tid;   // V[64 d][64 k]
    const int d    = c >> 3;
    const int colb = (c & 7) << 4;
    const int srcb = colb ^ ((d & 7) << 4);
    async16(vbase + (size_t)d * SEQ + k0 + (srcb >> 1), VsB + c * 8);
  }
}

// ---------- flash attention: single-Q block, double-buffered KVBLK=64 ----------
// grid (32 bh, 32 qbpos) x 256 threads. qb = 31-blockIdx.y and x-fastest
// dispatch => globally longest-first (LPT) scheduling across all (bh, qb).
// LDS = 2*8K (K) + 2*8K (V) + 8K (P) = 40 KB -> 4 blocks/CU.
__global__ __launch_bounds__(256)
void attn_k(const unsigned short* __restrict__ Q,
            const unsigned short* __restrict__ Kp,
            const unsigned short* __restrict__ Vt,
            const int* __restrict__ pm,
            unsigned short* __restrict__ O) {
  __shared__ __align__(16) unsigned short Ks[2][64 * 64];
  __shared__ __align__(16) unsigned short Vs[2][64 * 64];
  __shared__ __align__(16) unsigned short plds[4][16 * 64];

  const int tid  = threadIdx.x;
  const int lane = tid & 63;
  const int w    = tid >> 6;
  const int lc = lane & 15, lg = lane >> 4;
  const int qb = 31 - blockIdx.y;          // globally longest-first
  const int bh = blockIdx.x;
  const int b  = bh >> 4, h = bh & 15;

  const size_t base = (size_t)bh * SEQ * HD;
  const unsigned short* kbase = Kp + base;
  const unsigned short* vbase = Vt + (size_t)bh * HD * SEQ;
  const int* pmb = pm + b * SEQ;
  char* pb = (char*)&plds[w][0];
  const int swp = (lc & 7) << 4;

  const int qrow0 = qb * 64 + w * 16;
  const int qrow  = qrow0 + lc;

  short8 qa[2];
  {
    const unsigned short* qp = Q + base + (size_t)qrow * HD + lg * 8;
    qa[0] = *(const short8*)(qp);
    qa[1] = *(const short8*)(qp + 32);
  }

  f32x4 oacc[4] = {};
  float mrow = -1e30f, lsum = 0.f;

  const int nk = qb + 1;                   // 64-wide k-tiles to the diagonal

  stage_kv64(kbase, vbase, 0, Ks[0], Vs[0], tid);
  __syncthreads();   // DMA(0) drained

  for (int kt = 0; kt < nk; ++kt) {
    const int cur = kt & 1;
    const int k0 = kt * 64;
    if (kt + 1 < nk)
      stage_kv64(kbase, vbase, k0 + 64, Ks[cur ^ 1], Vs[cur ^ 1], tid);

    // ---- QK^T swapped: mfma(K, Q) -> lane holds S[q=qrow][k-slice] ----
    f32x4 s[4];
    const char* kbuf = (const char*)Ks[cur];
    __builtin_amdgcn_s_setprio(1);
#pragma unroll
    for (int t = 0; t < 4; ++t) {
      const int row = t * 16 + lc;
      const int swk = (row & 7) << 4;
      const char* kr = kbuf + row * 128;
      short8 kb0 = *(const short8*)(kr + ((lg * 16) ^ swk));
      short8 kb1 = *(const short8*)(kr + ((lg * 16 + 64) ^ swk));
      f32x4 z = {};
      z = __builtin_amdgcn_mfma_f32_16x16x32_bf16(kb0, qa[0], z, 0, 0, 0);
      z = __builtin_amdgcn_mfma_f32_16x16x32_bf16(kb1, qa[1], z, 0, 0, 0);
      const int kr0 = k0 + t * 16;
      int4 pmv = *(const int4*)(pmb + kr0 + lg * 4);
#pragma unroll
      for (int r = 0; r < 4; ++r) {
        const int kidx = kr0 + lg * 4 + r;
        float sv = z[r] * 0.125f;                       // 1/sqrt(64)
        if (kidx > qrow || (&pmv.x)[r] == 0) sv = NEGV; // causal + padding
        s[t][r] = sv;
      }
    }
    __builtin_amdgcn_s_setprio(0);

    // ---- online softmax (local 16 + 2 shuffles), defer-max rescale ----
    float mx = -1e30f;
#pragma unroll
    for (int t = 0; t < 4; ++t)
      mx = fmaxf(mx, fmaxf(fmaxf(s[t][0], s[t][1]), fmaxf(s[t][2], s[t][3])));
    mx = fmaxf(mx, __shfl_xor(mx, 16, 64));
    mx = fmaxf(mx, __shfl_xor(mx, 32, 64));
    if (!__all(mx <= mrow + 8.f)) {
      const float mnew = fmaxf(mrow, mx);
      const float sc = __expf(mrow - mnew);
      lsum *= sc;
      mrow = mnew;
      const float s0 = __shfl(sc, lg * 4 + 0, 64);
      const float s1 = __shfl(sc, lg * 4 + 1, 64);
      const float s2 = __shfl(sc, lg * 4 + 2, 64);
      const float s3 = __shfl(sc, lg * 4 + 3, 64);
#pragma unroll
      for (int t = 0; t < 4; ++t) {
        oacc[t][0] *= s0; oacc[t][1] *= s1; oacc[t][2] *= s2; oacc[t][3] *= s3;
      }
    }
    float sum = 0.f;
#pragma unroll
    for (int t = 0; t < 4; ++t)
#pragma unroll
      for (int r = 0; r < 4; ++r) {
        const float p = __expf(s[t][r] - mrow);
        s[t][r] = p;
        sum += p;
      }
    sum += __shfl_xor(sum, 16, 64);
    sum += __shfl_xor(sum, 32, 64);
    lsum += sum;

    // ---- P -> per-wave LDS (bf16, swizzled), wave-synchronous ----
#pragma unroll
    for (int t = 0; t < 4; ++t) {
      short4 pk;
      pk.x = (short)f2bf(s[t][0]); pk.y = (short)f2bf(s[t][1]);
      pk.z = (short)f2bf(s[t][2]); pk.w = (short)f2bf(s[t][3]);
      const int colb = (t * 16 + lg * 4) * 2;
      *(short4*)(pb + lc * 128 + (colb ^ swp)) = pk;
    }
    short8 pa[2];
#pragma unroll
    for (int ks = 0; ks < 2; ++ks)
      pa[ks] = *(const short8*)(pb + lc * 128 + (((ks * 32 + lg * 8) * 2) ^ swp));

    // ---- PV: O += P @ V, V fragments from swizzled LDS ----
    const char* vbuf = (const char*)Vs[cur];
    __builtin_amdgcn_s_setprio(1);
#pragma unroll
    for (int t = 0; t < 4; ++t) {
      const int d = t * 16 + lc;
      const int swv = (d & 7) << 4;
      const char* vr = vbuf + d * 128;
#pragma unroll
      for (int ks = 0; ks < 2; ++ks) {
        short8 vv = *(const short8*)(vr + ((ks * 64 + lg * 16) ^ swv));
        oacc[t] = __builtin_amdgcn_mfma_f32_16x16x32_bf16(pa[ks], vv, oacc[t], 0, 0, 0);
      }
    }
    __builtin_amdgcn_s_setprio(0);

    __syncthreads();   // drains stage(kt+1) DMA; all waves done with buf[cur]
  }

  // ---- epilogue: normalize, store O[b, s, h*64+d] ----
  const float l0 = __shfl(lsum, lg * 4 + 0, 64);
  const float l1 = __shfl(lsum, lg * 4 + 1, 64);
  const float l2 = __shfl(lsum, lg * 4 + 2, 64);
  const float l3 = __shfl(lsum, lg * 4 + 3, 64);
  const float i0 = 1.f / l0, i1 = 1.f / l1, i2 = 1.f / l2, i3 = 1.f / l3;
#pragma unroll
  for (int t = 0; t < 4; ++t) {
    const size_t o0 = ((size_t)(b * SEQ + qrow0 + lg * 4)) * DIM + h * HD + t * 16 + lc;
    O[o0]           = f2bf(oacc[t][0] * i0);
    O[o0 + DIM]     = f2bf(oacc[t][1] * i1);
    O[o0 + 2 * DIM] = f2bf(oacc[t][2] * i2);
    O[o0 + 3 * DIM] = f2bf(oacc[t][3] * i3);
  }
}

extern "C" void kernel_launch(void* const* d_in, const int* in_sizes, int n_in,
                              void* d_out, int out_size, void* d_ws, size_t ws_size,
                              hipStream_t stream) {
  const float* x  = (const float*)d_in[0];
  const int*   pm = (const int*)d_in[1];
  const float* Wq = (const float*)d_in[3];
  const float* bq = (const float*)d_in[4];
  const float* Wk = (const float*)d_in[5];
  const float* bk = (const float*)d_in[6];
  const float* Wv = (const float*)d_in[7];
  const float* bv = (const float*)d_in[8];
  const float* Wo = (const float*)d_in[9];
  const float* bo = (const float*)d_in[10];

  const size_t NX = (size_t)4096 * 1024;
  const size_t NW = (size_t)1024 * 1024;

  unsigned short* ws  = (unsigned short*)d_ws;
  unsigned short* xb  = ws;
  unsigned short* wqb = xb + NX;
  unsigned short* wkb = wqb + NW;
  unsigned short* wvb = wkb + NW;
  unsigned short* wob = wvb + NW;
  unsigned short* Qb  = wob + NW;
  unsigned short* Kb  = Qb + NX;
  unsigned short* Vtb = Kb + NX;
  unsigned short* Ob  = xb;   // alias: x no longer needed after QKV GEMM

  cast_bf16_k<<<dim3(2048), dim3(256), 0, stream>>>(x, xb, (int)(NX / 4));
  cast_w4_k<<<dim3(512, 4), dim3(256), 0, stream>>>(Wq, Wk, Wv, Wo,
                                                    wqb, wkb, wvb, wob,
                                                    (int)(NW / 4));

  qkv_gemm_k<<<dim3(8, 32, 3), dim3(256), 0, stream>>>(xb, wqb, wkb, wvb,
                                                       bq, bk, bv, Qb, Kb, Vtb);

  attn_k<<<dim3(32, 32), dim3(256), 0, stream>>>(Qb, Kb, Vtb, pm, Ob);

  out_gemm_k<<<dim3(8, 32), dim3(256), 0, stream>>>(Ob, wob, bo, (float*)d_out);
}

// Round 9
// 123.181 us; speedup vs baseline: 1.4807x; 1.1584x over previous
//
#include <hip/hip_runtime.h>
#include <hip/hip_bf16.h>
#include <stdint.h>

#define SEQ 2048
#define DIM 1024
#define HEADS 16
#define HD 64
#define NEGV (-1e9f)
#define SCALE2 0.18033688011112042f   // 0.125 * log2(e)
#define THR2 11.541560327111707f      // 8 * log2(e)

typedef __attribute__((ext_vector_type(8))) short short8;
typedef __attribute__((ext_vector_type(4))) float f32x4;

__device__ __forceinline__ unsigned short f2bf(float f) {
  __hip_bfloat16 h = __float2bfloat16(f);
  union { __hip_bfloat16 h; unsigned short u; } cv;
  cv.h = h;
  return cv.u;
}

__device__ __forceinline__ void async16(const void* g, void* l) {
  __builtin_amdgcn_global_load_lds(
      (const __attribute__((address_space(1))) unsigned int*)g,
      (__attribute__((address_space(3))) unsigned int*)l, 16, 0, 0);
}

// ---------- fp32 -> bf16 cast, float4 vectorized ----------
__global__ void cast_bf16_k(const float* __restrict__ in,
                            unsigned short* __restrict__ out, int n4) {
  int stride = gridDim.x * blockDim.x;
  for (int i = blockIdx.x * blockDim.x + threadIdx.x; i < n4; i += stride) {
    float4 v = ((const float4*)in)[i];
    ushort4 o;
    o.x = f2bf(v.x); o.y = f2bf(v.y); o.z = f2bf(v.z); o.w = f2bf(v.w);
    ((ushort4*)out)[i] = o;
  }
}

// fused 4-weight cast: blockIdx.y selects the matrix
__global__ void cast_w4_k(const float* __restrict__ w0, const float* __restrict__ w1,
                          const float* __restrict__ w2, const float* __restrict__ w3,
                          unsigned short* __restrict__ o0, unsigned short* __restrict__ o1,
                          unsigned short* __restrict__ o2, unsigned short* __restrict__ o3,
                          int n4) {
  const float* in = (blockIdx.y == 0) ? w0 : (blockIdx.y == 1) ? w1
                   : (blockIdx.y == 2) ? w2 : w3;
  unsigned short* out = (blockIdx.y == 0) ? o0 : (blockIdx.y == 1) ? o1
                       : (blockIdx.y == 2) ? o2 : o3;
  int stride = gridDim.x * blockDim.x;
  for (int i = blockIdx.x * blockDim.x + threadIdx.x; i < n4; i += stride) {
    float4 v = ((const float4*)in)[i];
    ushort4 o;
    o.x = f2bf(v.x); o.y = f2bf(v.y); o.z = f2bf(v.z); o.w = f2bf(v.w);
    ((ushort4*)out)[i] = o;
  }
}

// ---------- shared GEMM core: C[128x128] tile, A[M,K] bf16, B[N,K] bf16 (B^T input) ----------
__device__ __forceinline__ void gemm_core(const unsigned short* __restrict__ A,
                                          const unsigned short* __restrict__ B,
                                          int K, int bm0, int bn0,
                                          unsigned short* As, unsigned short* Bs,
                                          f32x4 acc[4][4]) {
  const int tid  = threadIdx.x;
  const int lane = tid & 63;
  const int w    = tid >> 6;
  const int wr   = w >> 1, wc = w & 1;
  const int lrow = lane & 15, lkg = lane >> 4;

  for (int k0 = 0; k0 < K; k0 += 32) {
#pragma unroll
    for (int i = 0; i < 2; ++i) {
      int e   = (i * 256 + tid) * 8;
      int row = e >> 5;
      int kk  = e & 31;
      async16(A + (size_t)(bm0 + row) * K + (size_t)(k0 + kk), As + e);
      async16(B + (size_t)(bn0 + row) * K + (size_t)(k0 + kk), Bs + e);
    }
    __syncthreads();

    short8 af[4], bf[4];
#pragma unroll
    for (int i = 0; i < 4; ++i) {
      af[i] = *(const short8*)(As + (wr * 64 + i * 16 + lrow) * 32 + lkg * 8);
      bf[i] = *(const short8*)(Bs + (wc * 64 + i * 16 + lrow) * 32 + lkg * 8);
    }
#pragma unroll
    for (int i = 0; i < 4; ++i)
#pragma unroll
      for (int j = 0; j < 4; ++j)
        acc[i][j] = __builtin_amdgcn_mfma_f32_16x16x32_bf16(af[i], bf[j], acc[i][j], 0, 0, 0);
    __syncthreads();
  }
}

// ---------- fused QKV projection ----------
__global__ __launch_bounds__(256)
void qkv_gemm_k(const unsigned short* __restrict__ xb,
                const unsigned short* __restrict__ wqb,
                const unsigned short* __restrict__ wkb,
                const unsigned short* __restrict__ wvb,
                const float* __restrict__ bq, const float* __restrict__ bk,
                const float* __restrict__ bv,
                unsigned short* __restrict__ Qb, unsigned short* __restrict__ Kb,
                unsigned short* __restrict__ Vtb) {
  __shared__ __align__(16) unsigned short As[128 * 32];
  __shared__ __align__(16) unsigned short Bs[128 * 32];
  const int z = blockIdx.z;
  const unsigned short* B = (z == 0) ? wqb : (z == 1) ? wkb : wvb;
  const float* bias       = (z == 0) ? bq  : (z == 1) ? bk  : bv;
  const int bm0 = blockIdx.y * 128, bn0 = blockIdx.x * 128;

  f32x4 acc[4][4] = {};
  gemm_core(xb, B, DIM, bm0, bn0, As, Bs, acc);

  const int lane = threadIdx.x & 63;
  const int w = threadIdx.x >> 6, wr = w >> 1, wc = w & 1;
  unsigned short* out01 = (z == 0) ? Qb : Kb;
#pragma unroll
  for (int i = 0; i < 4; ++i)
#pragma unroll
    for (int j = 0; j < 4; ++j)
#pragma unroll
      for (int r = 0; r < 4; ++r) {
        int mg = bm0 + wr * 64 + i * 16 + (lane >> 4) * 4 + r;
        int ng = bn0 + wc * 64 + j * 16 + (lane & 15);
        float v = acc[i][j][r] + bias[ng];
        int bb = mg >> 11, s = mg & 2047, h = ng >> 6, d = ng & 63;
        int bh = bb * HEADS + h;
        if (z < 2)
          out01[((size_t)bh * SEQ + s) * HD + d] = f2bf(v);   // [b,h,s,d]
        else
          Vtb[((size_t)bh * HD + d) * SEQ + s] = f2bf(v);     // [b,h,d,s]
      }
}

// ---------- output projection (fp32 out + bias) ----------
__global__ __launch_bounds__(256)
void out_gemm_k(const unsigned short* __restrict__ Ob,
                const unsigned short* __restrict__ wob,
                const float* __restrict__ bo, float* __restrict__ out) {
  __shared__ __align__(16) unsigned short As[128 * 32];
  __shared__ __align__(16) unsigned short Bs[128 * 32];
  const int bm0 = blockIdx.y * 128, bn0 = blockIdx.x * 128;

  f32x4 acc[4][4] = {};
  gemm_core(Ob, wob, DIM, bm0, bn0, As, Bs, acc);

  const int lane = threadIdx.x & 63;
  const int w = threadIdx.x >> 6, wr = w >> 1, wc = w & 1;
#pragma unroll
  for (int i = 0; i < 4; ++i)
#pragma unroll
    for (int j = 0; j < 4; ++j)
#pragma unroll
      for (int r = 0; r < 4; ++r) {
        int mg = bm0 + wr * 64 + i * 16 + (lane >> 4) * 4 + r;
        int ng = bn0 + wc * 64 + j * 16 + (lane & 15);
        out[(size_t)mg * DIM + ng] = acc[i][j][r] + bo[ng];
      }
}

// ---------- attention: KVBLK=64 staging, swizzled source ----------
__device__ __forceinline__ void stage_kv64(const unsigned short* __restrict__ kbase,
                                           const unsigned short* __restrict__ vbase,
                                           int k0, unsigned short* KsB,
                                           unsigned short* VsB, int tid) {
#pragma unroll
  for (int j = 0; j < 2; ++j) {
    const int c    = j * 256 + tid;   // 512 chunks of 16B: K[64][64]
    const int row  = c >> 3;
    const int colb = (c & 7) << 4;
    const int srcb = colb ^ ((row & 7) << 4);
    async16(kbase + (size_t)(k0 + row) * HD + (srcb >> 1), KsB + c * 8);
  }
#pragma unroll
  for (int j = 0; j < 2; ++j) {
    const int c    = j * 256 + tid;   // V[64 d][64 k]
    const int d    = c >> 3;
    const int colb = (c & 7) << 4;
    const int srcb = colb ^ ((d & 7) << 4);
    async16(vbase + (size_t)d * SEQ + k0 + (srcb >> 1), VsB + c * 8);
  }
}

// ---------- flash attention: single-Q block, double-buffered KVBLK=64 ----------
// grid (32 bh, 32 qbpos) x 256 threads. qb = 31-blockIdx.y, x-fastest =>
// globally longest-first (LPT). LDS 40 KB -> 4 blocks/CU.
// Softmax in exp2 domain; cross-lane reduces only in the rare rescale branch
// and once in the epilogue (partial-lsum scheme). Mask work only on the
// diagonal tile when the padding mask is all-ones (checked once per block).
__global__ __launch_bounds__(256)
void attn_k(const unsigned short* __restrict__ Q,
            const unsigned short* __restrict__ Kp,
            const unsigned short* __restrict__ Vt,
            const int* __restrict__ pm,
            unsigned short* __restrict__ O) {
  __shared__ __align__(16) unsigned short Ks[2][64 * 64];
  __shared__ __align__(16) unsigned short Vs[2][64 * 64];
  __shared__ __align__(16) unsigned short plds[4][16 * 64];
  __shared__ int wflag[4];

  const int tid  = threadIdx.x;
  const int lane = tid & 63;
  const int w    = tid >> 6;
  const int lc = lane & 15, lg = lane >> 4;
  const int qb = 31 - blockIdx.y;          // globally longest-first
  const int bh = blockIdx.x;
  const int b  = bh >> 4, h = bh & 15;

  const size_t base = (size_t)bh * SEQ * HD;
  const unsigned short* kbase = Kp + base;
  const unsigned short* vbase = Vt + (size_t)bh * HD * SEQ;
  const int* pmb = pm + b * SEQ;
  char* pb = (char*)&plds[w][0];
  const int swp = (lc & 7) << 4;

  const int qrow0 = qb * 64 + w * 16;
  const int qrow  = qrow0 + lc;

  short8 qa[2];
  {
    const unsigned short* qp = Q + base + (size_t)qrow * HD + lg * 8;
    qa[0] = *(const short8*)(qp);
    qa[1] = *(const short8*)(qp + 32);
  }

  f32x4 oacc[4] = {};
  float mrow = -1e30f, lsum = 0.f;

  const int nk = qb + 1;                   // 64-wide k-tiles to the diagonal

  stage_kv64(kbase, vbase, 0, Ks[0], Vs[0], tid);

  // one-time padding-mask scan (overlaps DMA(0)); wflag avoids atomics
  {
    int ok = 1;
    for (int i = tid; i < SEQ / 4; i += 256) {
      int4 v = ((const int4*)pmb)[i];
      ok &= (v.x != 0) & (v.y != 0) & (v.z != 0) & (v.w != 0);
    }
    ok = __all(ok) ? 1 : 0;
    if (lane == 0) wflag[w] = ok;
  }
  __syncthreads();   // DMA(0) drained + wflag visible
  const bool allones = (wflag[0] & wflag[1] & wflag[2] & wflag[3]) != 0;

  for (int kt = 0; kt < nk; ++kt) {
    const int cur = kt & 1;
    const int k0 = kt * 64;
    if (kt + 1 < nk)
      stage_kv64(kbase, vbase, k0 + 64, Ks[cur ^ 1], Vs[cur ^ 1], tid);

    // ---- QK^T swapped: mfma(K, Q) -> lane holds S[q=qrow][k-slice] ----
    f32x4 s[4];
    const char* kbuf = (const char*)Ks[cur];
    __builtin_amdgcn_s_setprio(1);
#pragma unroll
    for (int t = 0; t < 4; ++t) {
      const int row = t * 16 + lc;
      const int swk = (row & 7) << 4;
      const char* kr = kbuf + row * 128;
      short8 kb0 = *(const short8*)(kr + ((lg * 16) ^ swk));
      short8 kb1 = *(const short8*)(kr + ((lg * 16 + 64) ^ swk));
      f32x4 z = {};
      z = __builtin_amdgcn_mfma_f32_16x16x32_bf16(kb0, qa[0], z, 0, 0, 0);
      z = __builtin_amdgcn_mfma_f32_16x16x32_bf16(kb1, qa[1], z, 0, 0, 0);
#pragma unroll
      for (int r = 0; r < 4; ++r) s[t][r] = z[r] * SCALE2;   // log2-domain
    }
    __builtin_amdgcn_s_setprio(0);

    // ---- masks: full work only if padding has zeros; else diagonal only ----
    if (!allones) {
#pragma unroll
      for (int t = 0; t < 4; ++t) {
        const int kr0 = k0 + t * 16;
        int4 pmv = *(const int4*)(pmb + kr0 + lg * 4);
#pragma unroll
        for (int r = 0; r < 4; ++r) {
          const int kidx = kr0 + lg * 4 + r;
          if (kidx > qrow || (&pmv.x)[r] == 0) s[t][r] = NEGV;
        }
      }
    } else if (kt == qb) {
#pragma unroll
      for (int t = 0; t < 4; ++t)
#pragma unroll
        for (int r = 0; r < 4; ++r) {
          const int kidx = k0 + t * 16 + lg * 4 + r;
          if (kidx > qrow) s[t][r] = NEGV;
        }
    }

    // ---- online softmax: shuffle-free common path (defer-max) ----
    float mx = -1e30f;
#pragma unroll
    for (int t = 0; t < 4; ++t)
      mx = fmaxf(mx, fmaxf(fmaxf(s[t][0], s[t][1]), fmaxf(s[t][2], s[t][3])));
    if (!__all(mx <= mrow + THR2)) {       // rare: true row max + rescale
      mx = fmaxf(mx, __shfl_xor(mx, 16, 64));
      mx = fmaxf(mx, __shfl_xor(mx, 32, 64));
      const float mnew = fmaxf(mrow, mx);
      const float sc = exp2f(mrow - mnew);
      lsum *= sc;
      mrow = mnew;
      const float s0 = __shfl(sc, lg * 4 + 0, 64);
      const float s1 = __shfl(sc, lg * 4 + 1, 64);
      const float s2 = __shfl(sc, lg * 4 + 2, 64);
      const float s3 = __shfl(sc, lg * 4 + 3, 64);
#pragma unroll
      for (int t = 0; t < 4; ++t) {
        oacc[t][0] *= s0; oacc[t][1] *= s1; oacc[t][2] *= s2; oacc[t][3] *= s3;
      }
    }
    float sum = 0.f;
#pragma unroll
    for (int t = 0; t < 4; ++t)
#pragma unroll
      for (int r = 0; r < 4; ++r) {
        const float p = exp2f(s[t][r] - mrow);
        s[t][r] = p;
        sum += p;
      }
    lsum += sum;                           // per-lane partial; reduced at end

    // ---- P -> per-wave LDS (bf16, swizzled), wave-synchronous ----
#pragma unroll
    for (int t = 0; t < 4; ++t) {
      short4 pk;
      pk.x = (short)f2bf(s[t][0]); pk.y = (short)f2bf(s[t][1]);
      pk.z = (short)f2bf(s[t][2]); pk.w = (short)f2bf(s[t][3]);
      const int colb = (t * 16 + lg * 4) * 2;
      *(short4*)(pb + lc * 128 + (colb ^ swp)) = pk;
    }
    short8 pa[2];
#pragma unroll
    for (int ks = 0; ks < 2; ++ks)
      pa[ks] = *(const short8*)(pb + lc * 128 + (((ks * 32 + lg * 8) * 2) ^ swp));

    // ---- PV: O += P @ V, V fragments from swizzled LDS ----
    const char* vbuf = (const char*)Vs[cur];
    __builtin_amdgcn_s_setprio(1);
#pragma unroll
    for (int t = 0; t < 4; ++t) {
      const int d = t * 16 + lc;
      const int swv = (d & 7) << 4;
      const char* vr = vbuf + d * 128;
#pragma unroll
      for (int ks = 0; ks < 2; ++ks) {
        short8 vv = *(const short8*)(vr + ((ks * 64 + lg * 16) ^ swv));
        oacc[t] = __builtin_amdgcn_mfma_f32_16x16x32_bf16(pa[ks], vv, oacc[t], 0, 0, 0);
      }
    }
    __builtin_amdgcn_s_setprio(0);

    __syncthreads();   // drains stage(kt+1) DMA; all waves done with buf[cur]
  }

  // ---- epilogue: reduce partial lsum across the 4 row-copies, store ----
  lsum += __shfl_xor(lsum, 16, 64);
  lsum += __shfl_xor(lsum, 32, 64);
  const float l0 = __shfl(lsum, lg * 4 + 0, 64);
  const float l1 = __shfl(lsum, lg * 4 + 1, 64);
  const float l2 = __shfl(lsum, lg * 4 + 2, 64);
  const float l3 = __shfl(lsum, lg * 4 + 3, 64);
  const float i0 = 1.f / l0, i1 = 1.f / l1, i2 = 1.f / l2, i3 = 1.f / l3;
#pragma unroll
  for (int t = 0; t < 4; ++t) {
    const size_t o0 = ((size_t)(b * SEQ + qrow0 + lg * 4)) * DIM + h * HD + t * 16 + lc;
    O[o0]           = f2bf(oacc[t][0] * i0);
    O[o0 + DIM]     = f2bf(oacc[t][1] * i1);
    O[o0 + 2 * DIM] = f2bf(oacc[t][2] * i2);
    O[o0 + 3 * DIM] = f2bf(oacc[t][3] * i3);
  }
}

extern "C" void kernel_launch(void* const* d_in, const int* in_sizes, int n_in,
                              void* d_out, int out_size, void* d_ws, size_t ws_size,
                              hipStream_t stream) {
  const float* x  = (const float*)d_in[0];
  const int*   pm = (const int*)d_in[1];
  const float* Wq = (const float*)d_in[3];
  const float* bq = (const float*)d_in[4];
  const float* Wk = (const float*)d_in[5];
  const float* bk = (const float*)d_in[6];
  const float* Wv = (const float*)d_in[7];
  const float* bv = (const float*)d_in[8];
  const float* Wo = (const float*)d_in[9];
  const float* bo = (const float*)d_in[10];

  const size_t NX = (size_t)4096 * 1024;
  const size_t NW = (size_t)1024 * 1024;

  unsigned short* ws  = (unsigned short*)d_ws;
  unsigned short* xb  = ws;
  unsigned short* wqb = xb + NX;
  unsigned short* wkb = wqb + NW;
  unsigned short* wvb = wkb + NW;
  unsigned short* wob = wvb + NW;
  unsigned short* Qb  = wob + NW;
  unsigned short* Kb  = Qb + NX;
  unsigned short* Vtb = Kb + NX;
  unsigned short* Ob  = xb;   // alias: x no longer needed after QKV GEMM

  cast_bf16_k<<<dim3(2048), dim3(256), 0, stream>>>(x, xb, (int)(NX / 4));
  cast_w4_k<<<dim3(512, 4), dim3(256), 0, stream>>>(Wq, Wk, Wv, Wo,
                                                    wqb, wkb, wvb, wob,
                                                    (int)(NW / 4));

  qkv_gemm_k<<<dim3(8, 32, 3), dim3(256), 0, stream>>>(xb, wqb, wkb, wvb,
                                                       bq, bk, bv, Qb, Kb, Vtb);

  attn_k<<<dim3(32, 32), dim3(256), 0, stream>>>(Qb, Kb, Vtb, pm, Ob);

  out_gemm_k<<<dim3(8, 32), dim3(256), 0, stream>>>(Ob, wob, bo, (float*)d_out);
}